// Round 2
// baseline (520.119 us; speedup 1.0000x reference)
//
#include <hip/hip_runtime.h>
#include <cstdint>
#include <cstddef>

#define D_MODEL 1024
#define HD 64
#define NH 16
#define SEQ 2048
#define NB 2

typedef __attribute__((ext_vector_type(8))) short bf8;           // 8 bf16 (4 VGPR)
typedef __attribute__((ext_vector_type(8))) unsigned short us8;
typedef __attribute__((ext_vector_type(4))) unsigned short us4;
typedef __attribute__((ext_vector_type(4))) float f4;

__device__ __forceinline__ float bf2f(unsigned short u) {
  union { unsigned int i; float f; } c; c.i = ((unsigned int)u) << 16; return c.f;
}
__device__ __forceinline__ unsigned short f2bf(float x) {
  union { float f; unsigned int i; } c; c.f = x;
  unsigned int r = (c.i + 0x7FFFu + ((c.i >> 16) & 1u)) >> 16;   // RNE
  return (unsigned short)r;
}
__device__ __forceinline__ f4 mfma16(bf8 a, bf8 b, f4 c) {
  return __builtin_amdgcn_mfma_f32_16x16x32_bf16(a, b, c, 0, 0, 0);
}

#define QSCALE (0.125f * 1.44269504088896f)   // 1/sqrt(64) * log2(e)

// ---------------- prep: transpose + hi/lo split of the 4 weight matrices ----------------
__global__ __launch_bounds__(256) void prep_weights(
    const float* __restrict__ Wq, const float* __restrict__ Wk,
    const float* __restrict__ Wv, const float* __restrict__ Wo,
    unsigned short* __restrict__ wthi, unsigned short* __restrict__ wtlo) {
  int mat = blockIdx.z;
  const float* W = (mat == 0) ? Wq : (mat == 1) ? Wk : (mat == 2) ? Wv : Wo;
  unsigned short* oh = wthi + (size_t)mat * D_MODEL * D_MODEL;
  unsigned short* ol = wtlo + (size_t)mat * D_MODEL * D_MODEL;
  __shared__ float ls[32][33];
  int nt = blockIdx.x * 32, kt = blockIdx.y * 32;
  int i = threadIdx.x >> 5;   // 0..7
  int j = threadIdx.x & 31;
#pragma unroll
  for (int ii = 0; ii < 4; ++ii) {
    int r = i + ii * 8;
    ls[r][j] = W[(size_t)(kt + r) * D_MODEL + nt + j];
  }
  __syncthreads();
#pragma unroll
  for (int ii = 0; ii < 4; ++ii) {
    int r = i + ii * 8;                       // n-offset
    float v = ls[j][r];                       // = W[kt+j][nt+r]
    unsigned short h = f2bf(v);
    size_t o = (size_t)(nt + r) * D_MODEL + kt + j;
    oh[o] = h;
    ol[o] = f2bf(v - bf2f(h));
  }
}

// ---------------- fused q/k/v projection ----------------
// z=0: q (scaled by QSCALE, hi only), z=1: k (hi+lo), z=2: v -> TRANSPOSED vt[B,H,d,S]
// grid (8, 32, 3), block 256 (4 waves, 2x2, each 64x64)
// single barrier per K-step: double-buffered A staging, next-tile loads issued pre-MFMA
__global__ __launch_bounds__(256, 3) void proj_kernel(
    const float* __restrict__ Qin, const float* __restrict__ Kin, const float* __restrict__ Vin,
    const unsigned short* __restrict__ wthi, const unsigned short* __restrict__ wtlo,
    const float* __restrict__ bq, const float* __restrict__ bk, const float* __restrict__ bv,
    unsigned short* __restrict__ qh, unsigned short* __restrict__ kh,
    unsigned short* __restrict__ kl, unsigned short* __restrict__ vt) {
  int z = blockIdx.z;
  const float* A = (z == 0) ? Qin : (z == 1) ? Kin : Vin;
  const unsigned short* Bh = wthi + (size_t)z * D_MODEL * D_MODEL;
  const unsigned short* Bl = wtlo + (size_t)z * D_MODEL * D_MODEL;
  const float* bias = (z == 0) ? bq : (z == 1) ? bk : bv;
  int bm = blockIdx.y, bn = blockIdx.x;
  int tid = threadIdx.x;
  int lane = tid & 63, wave = tid >> 6;
  int wr = wave >> 1, wc = wave & 1;
  int l16 = lane & 15, l4 = lane >> 4;

  __shared__ unsigned short As[2][128 * 40];

  f4 acc[4][4];
  const f4 zf = {0.f, 0.f, 0.f, 0.f};
#pragma unroll
  for (int m = 0; m < 4; ++m)
#pragma unroll
    for (int n = 0; n < 4; ++n) acc[m][n] = zf;

  int rr = tid >> 2, c8 = (tid & 3) * 8;

  float4 x[2][2];
#pragma unroll
  for (int p = 0; p < 2; ++p) {
    const float* src = A + (size_t)(bm * 128 + p * 64 + rr) * D_MODEL + c8;
    x[p][0] = *reinterpret_cast<const float4*>(src);
    x[p][1] = *reinterpret_cast<const float4*>(src + 4);
  }
#pragma unroll
  for (int p = 0; p < 2; ++p) {
    us8 hv;
    hv[0] = f2bf(x[p][0].x); hv[1] = f2bf(x[p][0].y); hv[2] = f2bf(x[p][0].z); hv[3] = f2bf(x[p][0].w);
    hv[4] = f2bf(x[p][1].x); hv[5] = f2bf(x[p][1].y); hv[6] = f2bf(x[p][1].z); hv[7] = f2bf(x[p][1].w);
    *reinterpret_cast<us8*>(&As[0][(p * 64 + rr) * 40 + c8]) = hv;
  }
  __syncthreads();

  int cur = 0;
  for (int i = 0; i < 32; ++i) {
    int kt = i * 32;
    // prefetch next A tile into registers (latency hides under MFMAs)
    float4 nx[2][2];
    if (i < 31) {
#pragma unroll
      for (int p = 0; p < 2; ++p) {
        const float* src = A + (size_t)(bm * 128 + p * 64 + rr) * D_MODEL + kt + 32 + c8;
        nx[p][0] = *reinterpret_cast<const float4*>(src);
        nx[p][1] = *reinterpret_cast<const float4*>(src + 4);
      }
    }
    bf8 a[4], bhf[4], blf[4];
#pragma unroll
    for (int m = 0; m < 4; ++m)
      a[m] = *reinterpret_cast<const bf8*>(&As[cur][(wr * 64 + m * 16 + l16) * 40 + l4 * 8]);
#pragma unroll
    for (int n = 0; n < 4; ++n) {
      size_t off = (size_t)(bn * 128 + wc * 64 + n * 16 + l16) * D_MODEL + kt + l4 * 8;
      bhf[n] = *reinterpret_cast<const bf8*>(Bh + off);
      blf[n] = *reinterpret_cast<const bf8*>(Bl + off);
    }
#pragma unroll
    for (int m = 0; m < 4; ++m)
#pragma unroll
      for (int n = 0; n < 4; ++n) {
        acc[m][n] = mfma16(a[m], bhf[n], acc[m][n]);
        acc[m][n] = mfma16(a[m], blf[n], acc[m][n]);
      }
    if (i < 31) {
#pragma unroll
      for (int p = 0; p < 2; ++p) {
        us8 hv;
        hv[0] = f2bf(nx[p][0].x); hv[1] = f2bf(nx[p][0].y); hv[2] = f2bf(nx[p][0].z); hv[3] = f2bf(nx[p][0].w);
        hv[4] = f2bf(nx[p][1].x); hv[5] = f2bf(nx[p][1].y); hv[6] = f2bf(nx[p][1].z); hv[7] = f2bf(nx[p][1].w);
        *reinterpret_cast<us8*>(&As[cur ^ 1][(p * 64 + rr) * 40 + c8]) = hv;
      }
    }
    __syncthreads();
    cur ^= 1;
  }

#pragma unroll
  for (int n = 0; n < 4; ++n) {
    int col = bn * 128 + wc * 64 + n * 16 + l16;
    float bb = bias[col];
#pragma unroll
    for (int m = 0; m < 4; ++m) {
      int row0 = bm * 128 + wr * 64 + m * 16 + l4 * 4;
      if (z == 0) {
#pragma unroll
        for (int r = 0; r < 4; ++r)
          qh[(size_t)(row0 + r) * D_MODEL + col] = f2bf((acc[m][n][r] + bb) * QSCALE);
      } else if (z == 1) {
#pragma unroll
        for (int r = 0; r < 4; ++r) {
          float val = acc[m][n][r] + bb;
          unsigned short hh = f2bf(val);
          size_t o = (size_t)(row0 + r) * D_MODEL + col;
          kh[o] = hh; kl[o] = f2bf(val - bf2f(hh));
        }
      } else {
        // transposed store: vt[((b*NH+h)*HD + d)*SEQ + s], 4 consecutive tokens packed
        int bb2 = row0 >> 11, ss = row0 & (SEQ - 1);
        int hh2 = col >> 6, dd = col & 63;
        us4 pk;
#pragma unroll
        for (int r = 0; r < 4; ++r) pk[r] = f2bf(acc[m][n][r] + bb);
        *reinterpret_cast<us4*>(vt + ((size_t)(bb2 * NH + hh2) * HD + dd) * SEQ + ss) = pk;
      }
    }
  }
}

// ---------------- flash attention, barrier-free ----------------
// grid (S/64, NH, NB), block 256 = 4 independent waves; each wave owns 16 q-rows.
// V^T comes straight from global (L2-resident); only LDS use is the wave-private
// P transpose buffer -> zero __syncthreads in the whole kernel.
__global__ __launch_bounds__(256, 4) void attn_kernel(
    const unsigned short* __restrict__ qh, const unsigned short* __restrict__ kh,
    const unsigned short* __restrict__ kl, const unsigned short* __restrict__ vt,
    unsigned short* __restrict__ aout) {
  int qt = blockIdx.x, h = blockIdx.y, b = blockIdx.z;
  int tid = threadIdx.x;
  int lane = tid & 63, wave = tid >> 6;
  int l16 = lane & 15, l4 = lane >> 4;

  __shared__ unsigned short Pl[4][16 * 80];   // wave-private P, XOR-swizzled cols
  unsigned short* Pw = Pl[wave];

  const size_t qoff = (size_t)(b * SEQ + qt * 64 + wave * 16 + l16) * D_MODEL + h * HD + l4 * 8;
  bf8 qf0 = *reinterpret_cast<const bf8*>(qh + qoff);
  bf8 qf1 = *reinterpret_cast<const bf8*>(qh + qoff + 32);

  const unsigned short* Kh = kh + (size_t)b * SEQ * D_MODEL + h * HD;
  const unsigned short* Kl = kl + (size_t)b * SEQ * D_MODEL + h * HD;
  const unsigned short* Vt = vt + (size_t)(b * NH + h) * HD * SEQ;

  const f4 zf = {0.f, 0.f, 0.f, 0.f};
  f4 acc[4];
#pragma unroll
  for (int nt = 0; nt < 4; ++nt) acc[nt] = zf;
  float mrow[4] = {-1e30f, -1e30f, -1e30f, -1e30f};
  float lrow[4] = {0.f, 0.f, 0.f, 0.f};

  for (int kv = 0; kv < SEQ / 64; ++kv) {
    int k0 = kv * 64;
    // QK^T, 2-term split: q_hi·(k_hi + k_lo); scores already in log2 domain
    f4 sc[4];
#pragma unroll
    for (int c = 0; c < 4; ++c) {
      size_t koff = (size_t)(k0 + c * 16 + l16) * D_MODEL + l4 * 8;
      bf8 kh0 = *reinterpret_cast<const bf8*>(Kh + koff);
      bf8 kh1 = *reinterpret_cast<const bf8*>(Kh + koff + 32);
      bf8 kl0 = *reinterpret_cast<const bf8*>(Kl + koff);
      bf8 kl1 = *reinterpret_cast<const bf8*>(Kl + koff + 32);
      f4 s = zf;
      s = mfma16(qf0, kh0, s);
      s = mfma16(qf1, kh1, s);
      s = mfma16(qf0, kl0, s);
      s = mfma16(qf1, kl1, s);
      sc[c] = s;
    }
    // online softmax (base 2)
    float alpha[4];
#pragma unroll
    for (int r = 0; r < 4; ++r) {
      float mx = fmaxf(fmaxf(sc[0][r], sc[1][r]), fmaxf(sc[2][r], sc[3][r]));
      mx = fmaxf(mx, __shfl_xor(mx, 1));
      mx = fmaxf(mx, __shfl_xor(mx, 2));
      mx = fmaxf(mx, __shfl_xor(mx, 4));
      mx = fmaxf(mx, __shfl_xor(mx, 8));
      float mn = fmaxf(mrow[r], mx);
      alpha[r] = exp2f(mrow[r] - mn);
      mrow[r] = mn;
      float rs = 0.f;
#pragma unroll
      for (int c = 0; c < 4; ++c) {
        float p = exp2f(sc[c][r] - mn);
        sc[c][r] = p;
        rs += p;
      }
      rs += __shfl_xor(rs, 1);
      rs += __shfl_xor(rs, 2);
      rs += __shfl_xor(rs, 4);
      rs += __shfl_xor(rs, 8);
      lrow[r] = lrow[r] * alpha[r] + rs;
    }
    // V^T B-frags from global: latency covered by P LDS round-trip + TLP
    bf8 vb0[4], vb1[4];
#pragma unroll
    for (int nt = 0; nt < 4; ++nt) {
      const unsigned short* vp = Vt + (size_t)(nt * 16 + l16) * SEQ + k0 + l4 * 8;
      vb0[nt] = *reinterpret_cast<const bf8*>(vp);
      vb1[nt] = *reinterpret_cast<const bf8*>(vp + 32);
    }
    // P (C-layout) -> wave-private LDS
#pragma unroll
    for (int c = 0; c < 4; ++c)
#pragma unroll
      for (int r = 0; r < 4; ++r) {
        int prow = l4 * 4 + r;
        Pw[prow * 80 + ((c * 16 + l16) ^ ((prow & 7) << 3))] = f2bf(sc[c][r]);
      }
    bf8 pa0 = *reinterpret_cast<const bf8*>(&Pw[l16 * 80 + ((l4 * 8) ^ ((l16 & 7) << 3))]);
    bf8 pa1 = *reinterpret_cast<const bf8*>(&Pw[l16 * 80 + ((32 + l4 * 8) ^ ((l16 & 7) << 3))]);
    // rescale + PV
#pragma unroll
    for (int nt = 0; nt < 4; ++nt) {
      acc[nt][0] *= alpha[0]; acc[nt][1] *= alpha[1];
      acc[nt][2] *= alpha[2]; acc[nt][3] *= alpha[3];
    }
#pragma unroll
    for (int nt = 0; nt < 4; ++nt) {
      acc[nt] = mfma16(pa0, vb0[nt], acc[nt]);
      acc[nt] = mfma16(pa1, vb1[nt], acc[nt]);
    }
  }
  // epilogue
  float inv[4];
#pragma unroll
  for (int r = 0; r < 4; ++r) inv[r] = 1.0f / lrow[r];
#pragma unroll
  for (int nt = 0; nt < 4; ++nt) {
    int col = h * HD + nt * 16 + l16;
#pragma unroll
    for (int r = 0; r < 4; ++r) {
      int row = b * SEQ + qt * 64 + wave * 16 + l4 * 4 + r;
      aout[(size_t)row * D_MODEL + col] = f2bf(acc[nt][r] * inv[r]);
    }
  }
}

// ---------------- output projection: out = attn @ Wo + bo (fp32 out) ----------------
// grid (8, 64), block 256; tile 64(M)x128(N), wave wc owns a 64x32 strip
__global__ __launch_bounds__(256) void out_gemm(
    const unsigned short* __restrict__ ah, const unsigned short* __restrict__ wthi,
    const unsigned short* __restrict__ wtlo, const float* __restrict__ bo,
    float* __restrict__ out) {
  const unsigned short* Bh = wthi + (size_t)3 * D_MODEL * D_MODEL;
  const unsigned short* Bl = wtlo + (size_t)3 * D_MODEL * D_MODEL;
  int bm = blockIdx.y, bn = blockIdx.x;
  int tid = threadIdx.x, lane = tid & 63, wc = tid >> 6;
  int l16 = lane & 15, l4 = lane >> 4;
  f4 acc[4][2];
  const f4 zf = {0.f, 0.f, 0.f, 0.f};
#pragma unroll
  for (int m = 0; m < 4; ++m)
#pragma unroll
    for (int n = 0; n < 2; ++n) acc[m][n] = zf;

  for (int kt = 0; kt < D_MODEL; kt += 32) {
    bf8 a[4], bhf[2], blf[2];
#pragma unroll
    for (int m = 0; m < 4; ++m)
      a[m] = *reinterpret_cast<const bf8*>(
          ah + (size_t)(bm * 64 + m * 16 + l16) * D_MODEL + kt + l4 * 8);
#pragma unroll
    for (int n = 0; n < 2; ++n) {
      size_t off = (size_t)(bn * 128 + wc * 32 + n * 16 + l16) * D_MODEL + kt + l4 * 8;
      bhf[n] = *reinterpret_cast<const bf8*>(Bh + off);
      blf[n] = *reinterpret_cast<const bf8*>(Bl + off);
    }
#pragma unroll
    for (int m = 0; m < 4; ++m)
#pragma unroll
      for (int n = 0; n < 2; ++n) {
        acc[m][n] = mfma16(a[m], bhf[n], acc[m][n]);
        acc[m][n] = mfma16(a[m], blf[n], acc[m][n]);
      }
  }
#pragma unroll
  for (int n = 0; n < 2; ++n) {
    int col = bn * 128 + wc * 32 + n * 16 + l16;
    float bb = bo[col];
#pragma unroll
    for (int m = 0; m < 4; ++m) {
      int row0 = bm * 64 + m * 16 + l4 * 4;
#pragma unroll
      for (int r = 0; r < 4; ++r)
        out[(size_t)(row0 + r) * D_MODEL + col] = acc[m][n][r] + bb;
    }
  }
}

extern "C" void kernel_launch(void* const* d_in, const int* in_sizes, int n_in,
                              void* d_out, int out_size, void* d_ws, size_t ws_size,
                              hipStream_t stream) {
  const float* Q  = (const float*)d_in[0];
  const float* K  = (const float*)d_in[1];
  const float* V  = (const float*)d_in[2];
  const float* Wq = (const float*)d_in[3];
  const float* bq = (const float*)d_in[4];
  const float* Wk = (const float*)d_in[5];
  const float* bk = (const float*)d_in[6];
  const float* Wv = (const float*)d_in[7];
  const float* bv = (const float*)d_in[8];
  const float* Wo = (const float*)d_in[9];
  const float* bo = (const float*)d_in[10];
  float* out = (float*)d_out;

  unsigned char* ws = (unsigned char*)d_ws;
  const size_t MB = 1024 * 1024;
  unsigned short* wthi = (unsigned short*)(ws);             // 4x [n][k] hi   (8 MB)
  unsigned short* wtlo = (unsigned short*)(ws + 8 * MB);    // 4x [n][k] lo   (8 MB)
  unsigned short* qh   = (unsigned short*)(ws + 16 * MB);   // q hi  [B,S,D]  (8 MB)
  unsigned short* kh   = (unsigned short*)(ws + 24 * MB);   // k hi           (8 MB)
  unsigned short* kl   = (unsigned short*)(ws + 32 * MB);   // k lo           (8 MB)
  unsigned short* vt   = (unsigned short*)(ws + 40 * MB);   // V^T [B,H,d,S]  (8 MB)
  unsigned short* ah   = (unsigned short*)(ws + 48 * MB);   // attn out hi    (8 MB)

  prep_weights<<<dim3(32, 32, 4), 256, 0, stream>>>(Wq, Wk, Wv, Wo, wthi, wtlo);
  proj_kernel<<<dim3(8, 32, 3), 256, 0, stream>>>(Q, K, V, wthi, wtlo, bq, bk, bv,
                                                  qh, kh, kl, vt);
  attn_kernel<<<dim3(32, NH, NB), 256, 0, stream>>>(qh, kh, kl, vt, ah);
  out_gemm<<<dim3(8, 64), 256, 0, stream>>>(ah, wthi, wtlo, bo, out);
}

// Round 3
// 303.678 us; speedup vs baseline: 1.7127x; 1.7127x over previous
//
#include <hip/hip_runtime.h>
#include <cstdint>
#include <cstddef>

#define D_MODEL 1024
#define HD 64
#define NH 16
#define SEQ 2048
#define NB 2

typedef __attribute__((ext_vector_type(8))) short bf8;           // 8 bf16 (4 VGPR)
typedef __attribute__((ext_vector_type(8))) unsigned short us8;
typedef __attribute__((ext_vector_type(4))) unsigned short us4;
typedef __attribute__((ext_vector_type(4))) float f4;

__device__ __forceinline__ float bf2f(unsigned short u) {
  union { unsigned int i; float f; } c; c.i = ((unsigned int)u) << 16; return c.f;
}
__device__ __forceinline__ unsigned short f2bf(float x) {
  union { float f; unsigned int i; } c; c.f = x;
  unsigned int r = (c.i + 0x7FFFu + ((c.i >> 16) & 1u)) >> 16;   // RNE
  return (unsigned short)r;
}
__device__ __forceinline__ f4 mfma16(bf8 a, bf8 b, f4 c) {
  return __builtin_amdgcn_mfma_f32_16x16x32_bf16(a, b, c, 0, 0, 0);
}
// async global->LDS, 16B per lane; LDS dest = wave-uniform base + lane*16
__device__ __forceinline__ void gl16(const unsigned short* g, unsigned short* l) {
  __builtin_amdgcn_global_load_lds(
      (const __attribute__((address_space(1))) unsigned int*)g,
      (__attribute__((address_space(3))) unsigned int*)l, 16, 0, 0);
}

#define QSCALE (0.125f * 1.44269504088896f)   // 1/sqrt(64) * log2(e)

// ---------------- prep: transpose + hi/lo split of the 4 weight matrices ----------------
__global__ __launch_bounds__(256) void prep_weights(
    const float* __restrict__ Wq, const float* __restrict__ Wk,
    const float* __restrict__ Wv, const float* __restrict__ Wo,
    unsigned short* __restrict__ wthi, unsigned short* __restrict__ wtlo) {
  int mat = blockIdx.z;
  const float* W = (mat == 0) ? Wq : (mat == 1) ? Wk : (mat == 2) ? Wv : Wo;
  unsigned short* oh = wthi + (size_t)mat * D_MODEL * D_MODEL;
  unsigned short* ol = wtlo + (size_t)mat * D_MODEL * D_MODEL;
  __shared__ float ls[32][33];
  int nt = blockIdx.x * 32, kt = blockIdx.y * 32;
  int i = threadIdx.x >> 5;   // 0..7
  int j = threadIdx.x & 31;
#pragma unroll
  for (int ii = 0; ii < 4; ++ii) {
    int r = i + ii * 8;
    ls[r][j] = W[(size_t)(kt + r) * D_MODEL + nt + j];
  }
  __syncthreads();
#pragma unroll
  for (int ii = 0; ii < 4; ++ii) {
    int r = i + ii * 8;                       // n-offset
    float v = ls[j][r];                       // = W[kt+j][nt+r]
    unsigned short h = f2bf(v);
    size_t o = (size_t)(nt + r) * D_MODEL + kt + j;
    oh[o] = h;
    ol[o] = f2bf(v - bf2f(h));
  }
}

// ---------------- fused q/k/v projection ----------------
// z=0: q (scaled by QSCALE), z=1: k, z=2: v -> TRANSPOSED vt[B,H,d,S]
// grid (8, 32, 3), block 256 (4 waves, 2x2, each 64x64)
__global__ __launch_bounds__(256, 3) void proj_kernel(
    const float* __restrict__ Qin, const float* __restrict__ Kin, const float* __restrict__ Vin,
    const unsigned short* __restrict__ wthi, const unsigned short* __restrict__ wtlo,
    const float* __restrict__ bq, const float* __restrict__ bk, const float* __restrict__ bv,
    unsigned short* __restrict__ qh, unsigned short* __restrict__ kh,
    unsigned short* __restrict__ vt) {
  int z = blockIdx.z;
  const float* A = (z == 0) ? Qin : (z == 1) ? Kin : Vin;
  const unsigned short* Bh = wthi + (size_t)z * D_MODEL * D_MODEL;
  const unsigned short* Bl = wtlo + (size_t)z * D_MODEL * D_MODEL;
  const float* bias = (z == 0) ? bq : (z == 1) ? bk : bv;
  int bm = blockIdx.y, bn = blockIdx.x;
  int tid = threadIdx.x;
  int lane = tid & 63, wave = tid >> 6;
  int wr = wave >> 1, wc = wave & 1;
  int l16 = lane & 15, l4 = lane >> 4;

  __shared__ unsigned short As[2][128 * 40];

  f4 acc[4][4];
  const f4 zf = {0.f, 0.f, 0.f, 0.f};
#pragma unroll
  for (int m = 0; m < 4; ++m)
#pragma unroll
    for (int n = 0; n < 4; ++n) acc[m][n] = zf;

  int rr = tid >> 2, c8 = (tid & 3) * 8;

  float4 x[2][2];
#pragma unroll
  for (int p = 0; p < 2; ++p) {
    const float* src = A + (size_t)(bm * 128 + p * 64 + rr) * D_MODEL + c8;
    x[p][0] = *reinterpret_cast<const float4*>(src);
    x[p][1] = *reinterpret_cast<const float4*>(src + 4);
  }
#pragma unroll
  for (int p = 0; p < 2; ++p) {
    us8 hv;
    hv[0] = f2bf(x[p][0].x); hv[1] = f2bf(x[p][0].y); hv[2] = f2bf(x[p][0].z); hv[3] = f2bf(x[p][0].w);
    hv[4] = f2bf(x[p][1].x); hv[5] = f2bf(x[p][1].y); hv[6] = f2bf(x[p][1].z); hv[7] = f2bf(x[p][1].w);
    *reinterpret_cast<us8*>(&As[0][(p * 64 + rr) * 40 + c8]) = hv;
  }
  __syncthreads();

  int cur = 0;
  for (int i = 0; i < 32; ++i) {
    int kt = i * 32;
    float4 nx[2][2];
    if (i < 31) {
#pragma unroll
      for (int p = 0; p < 2; ++p) {
        const float* src = A + (size_t)(bm * 128 + p * 64 + rr) * D_MODEL + kt + 32 + c8;
        nx[p][0] = *reinterpret_cast<const float4*>(src);
        nx[p][1] = *reinterpret_cast<const float4*>(src + 4);
      }
    }
    bf8 a[4], bhf[4], blf[4];
#pragma unroll
    for (int m = 0; m < 4; ++m)
      a[m] = *reinterpret_cast<const bf8*>(&As[cur][(wr * 64 + m * 16 + l16) * 40 + l4 * 8]);
#pragma unroll
    for (int n = 0; n < 4; ++n) {
      size_t off = (size_t)(bn * 128 + wc * 64 + n * 16 + l16) * D_MODEL + kt + l4 * 8;
      bhf[n] = *reinterpret_cast<const bf8*>(Bh + off);
      blf[n] = *reinterpret_cast<const bf8*>(Bl + off);
    }
#pragma unroll
    for (int m = 0; m < 4; ++m)
#pragma unroll
      for (int n = 0; n < 4; ++n) {
        acc[m][n] = mfma16(a[m], bhf[n], acc[m][n]);
        acc[m][n] = mfma16(a[m], blf[n], acc[m][n]);
      }
    if (i < 31) {
#pragma unroll
      for (int p = 0; p < 2; ++p) {
        us8 hv;
        hv[0] = f2bf(nx[p][0].x); hv[1] = f2bf(nx[p][0].y); hv[2] = f2bf(nx[p][0].z); hv[3] = f2bf(nx[p][0].w);
        hv[4] = f2bf(nx[p][1].x); hv[5] = f2bf(nx[p][1].y); hv[6] = f2bf(nx[p][1].z); hv[7] = f2bf(nx[p][1].w);
        *reinterpret_cast<us8*>(&As[cur ^ 1][(p * 64 + rr) * 40 + c8]) = hv;
      }
    }
    __syncthreads();
    cur ^= 1;
  }

#pragma unroll
  for (int n = 0; n < 4; ++n) {
    int col = bn * 128 + wc * 64 + n * 16 + l16;
    float bb = bias[col];
#pragma unroll
    for (int m = 0; m < 4; ++m) {
      int row0 = bm * 128 + wr * 64 + m * 16 + l4 * 4;
      if (z == 0) {
#pragma unroll
        for (int r = 0; r < 4; ++r)
          qh[(size_t)(row0 + r) * D_MODEL + col] = f2bf((acc[m][n][r] + bb) * QSCALE);
      } else if (z == 1) {
#pragma unroll
        for (int r = 0; r < 4; ++r)
          kh[(size_t)(row0 + r) * D_MODEL + col] = f2bf(acc[m][n][r] + bb);
      } else {
        // transposed store: vt[((b*NH+h)*HD + d)*SEQ + s], 4 consecutive tokens packed
        int bb2 = row0 >> 11, ss = row0 & (SEQ - 1);
        int hh2 = col >> 6, dd = col & 63;
        us4 pk;
#pragma unroll
        for (int r = 0; r < 4; ++r) pk[r] = f2bf(acc[m][n][r] + bb);
        *reinterpret_cast<us4*>(vt + ((size_t)(bb2 * NH + hh2) * HD + dd) * SEQ + ss) = pk;
      }
    }
  }
}

// ---------------- flash attention, cooperative LDS staging ----------------
// block = 256 (4 waves), each wave 32 q-rows -> 128 q-rows/block.
// grid 512 blocks (2/CU). Per KV-tile (64 keys): K-tile [64k][64d] + V^T-tile
// [64d][64k] async-staged to double-buffered LDS (global_load_lds, pre-swizzled
// source granules: g ^= row&7), one __syncthreads per tile.
__global__ __launch_bounds__(256) void attn_kernel(
    const unsigned short* __restrict__ qh, const unsigned short* __restrict__ kh,
    const unsigned short* __restrict__ vt, unsigned short* __restrict__ aout) {
  // XCD-aware bijective swizzle: 512 blocks, 8 XCDs -> 64 contiguous per XCD
  int orig = blockIdx.x + (blockIdx.y << 4) + (blockIdx.z << 8);
  int swz = ((orig & 7) << 6) + (orig >> 3);
  int qt = swz & 15, h = (swz >> 4) & 15, b = swz >> 8;

  int tid = threadIdx.x;
  int lane = tid & 63, w = tid >> 6;
  int l16 = lane & 15, l4 = lane >> 4;
  int l8r = lane >> 3, l8c = lane & 7;

  __shared__ unsigned short khl[2][64 * 64];   // [key][d], granule-swizzled
  __shared__ unsigned short vtl[2][64 * 64];   // [d][key], granule-swizzled
  __shared__ unsigned short Pl[4][32 * 80];    // wave-private P, XOR-swizzled
  unsigned short* Pw = Pl[w];

  const unsigned short* Kh = kh + (size_t)b * SEQ * D_MODEL + h * HD;
  const unsigned short* Vt = vt + (size_t)(b * NH + h) * HD * SEQ;

  // q A-frags: rows qt*128 + w*32 + m*16 + l16
  bf8 qf[2][2];
#pragma unroll
  for (int m = 0; m < 2; ++m) {
    size_t qo = (size_t)(b * SEQ + qt * 128 + w * 32 + m * 16 + l16) * D_MODEL + h * HD + l4 * 8;
    qf[m][0] = *reinterpret_cast<const bf8*>(qh + qo);
    qf[m][1] = *reinterpret_cast<const bf8*>(qh + qo + 32);
  }

  const f4 zf = {0.f, 0.f, 0.f, 0.f};
  f4 acc[2][4];
  float mrow[2][4], lrow[2][4];
#pragma unroll
  for (int m = 0; m < 2; ++m)
#pragma unroll
    for (int nt = 0; nt < 4; ++nt) acc[m][nt] = zf;
#pragma unroll
  for (int m = 0; m < 2; ++m)
#pragma unroll
    for (int r = 0; r < 4; ++r) { mrow[m][r] = -1e30f; lrow[m][r] = 0.f; }

  // source granule pre-swizzle: lane l covers (row = 8s + l>>3, granule (l&7)^((l>>3)&7))
  const int sgr = (l8c ^ l8r) * 8;   // swizzled source offset in shorts
  const int s1 = w, s2 = w + 4;      // this wave's two 1KB slices per tile

  // stage tile 0
  gl16(Kh + (size_t)(8 * s1 + l8r) * D_MODEL + sgr, &khl[0][s1 * 512]);
  gl16(Kh + (size_t)(8 * s2 + l8r) * D_MODEL + sgr, &khl[0][s2 * 512]);
  gl16(Vt + (size_t)(8 * s1 + l8r) * SEQ + sgr, &vtl[0][s1 * 512]);
  gl16(Vt + (size_t)(8 * s2 + l8r) * SEQ + sgr, &vtl[0][s2 * 512]);
  __syncthreads();

  int cur = 0;
  for (int kv = 0; kv < SEQ / 64; ++kv) {
    // stage next tile into buf^1 (in flight during compute; drained by barrier)
    if (kv < SEQ / 64 - 1) {
      int k0n = (kv + 1) * 64;
      gl16(Kh + (size_t)(k0n + 8 * s1 + l8r) * D_MODEL + sgr, &khl[cur ^ 1][s1 * 512]);
      gl16(Kh + (size_t)(k0n + 8 * s2 + l8r) * D_MODEL + sgr, &khl[cur ^ 1][s2 * 512]);
      gl16(Vt + (size_t)(8 * s1 + l8r) * SEQ + k0n + sgr, &vtl[cur ^ 1][s1 * 512]);
      gl16(Vt + (size_t)(8 * s2 + l8r) * SEQ + k0n + sgr, &vtl[cur ^ 1][s2 * 512]);
    }
    const unsigned short* khb = khl[cur];
    const unsigned short* vlb = vtl[cur];
    // K B-frags (swizzled read)
    bf8 kb[4][2];
#pragma unroll
    for (int c = 0; c < 4; ++c) {
      int row = c * 16 + l16, sw = l16 & 7;
      kb[c][0] = *reinterpret_cast<const bf8*>(&khb[row * 64 + ((l4 ^ sw) * 8)]);
      kb[c][1] = *reinterpret_cast<const bf8*>(&khb[row * 64 + (((4 + l4) ^ sw) * 8)]);
    }
    // QK^T (k hi only; scores in log2 domain)
    f4 sc[2][4];
#pragma unroll
    for (int m = 0; m < 2; ++m)
#pragma unroll
      for (int c = 0; c < 4; ++c) {
        f4 s = zf;
        s = mfma16(qf[m][0], kb[c][0], s);
        s = mfma16(qf[m][1], kb[c][1], s);
        sc[m][c] = s;
      }
    // V B-frags (independent of softmax; overlap its latency)
    bf8 vb[4][2];
#pragma unroll
    for (int nt = 0; nt < 4; ++nt) {
      int row = nt * 16 + l16, sw = l16 & 7;
      vb[nt][0] = *reinterpret_cast<const bf8*>(&vlb[row * 64 + ((l4 ^ sw) * 8)]);
      vb[nt][1] = *reinterpret_cast<const bf8*>(&vlb[row * 64 + (((4 + l4) ^ sw) * 8)]);
    }
    // online softmax (base 2), rows = m*16 + l4*4 + r over 16 lanes
    float alpha[2][4];
#pragma unroll
    for (int m = 0; m < 2; ++m)
#pragma unroll
      for (int r = 0; r < 4; ++r) {
        float mx = fmaxf(fmaxf(sc[m][0][r], sc[m][1][r]), fmaxf(sc[m][2][r], sc[m][3][r]));
        mx = fmaxf(mx, __shfl_xor(mx, 1));
        mx = fmaxf(mx, __shfl_xor(mx, 2));
        mx = fmaxf(mx, __shfl_xor(mx, 4));
        mx = fmaxf(mx, __shfl_xor(mx, 8));
        float mn = fmaxf(mrow[m][r], mx);
        alpha[m][r] = exp2f(mrow[m][r] - mn);
        mrow[m][r] = mn;
        float rs = 0.f;
#pragma unroll
        for (int c = 0; c < 4; ++c) {
          float p = exp2f(sc[m][c][r] - mn);
          sc[m][c][r] = p;
          rs += p;
        }
        rs += __shfl_xor(rs, 1);
        rs += __shfl_xor(rs, 2);
        rs += __shfl_xor(rs, 4);
        rs += __shfl_xor(rs, 8);
        lrow[m][r] = lrow[m][r] * alpha[m][r] + rs;
      }
    // P (C-layout) -> wave-private LDS (element (row,col) at row*80 + (col ^ ((row&7)<<3)))
#pragma unroll
    for (int m = 0; m < 2; ++m)
#pragma unroll
      for (int c = 0; c < 4; ++c)
#pragma unroll
        for (int r = 0; r < 4; ++r) {
          int prow = l4 * 4 + r;
          Pw[(m * 16 + prow) * 80 + ((c * 16 + l16) ^ ((prow & 7) << 3))] = f2bf(sc[m][c][r]);
        }
    bf8 pa[2][2];
#pragma unroll
    for (int m = 0; m < 2; ++m) {
      int sw = (l16 & 7) << 3;
      pa[m][0] = *reinterpret_cast<const bf8*>(&Pw[(m * 16 + l16) * 80 + ((l4 * 8) ^ sw)]);
      pa[m][1] = *reinterpret_cast<const bf8*>(&Pw[(m * 16 + l16) * 80 + ((32 + l4 * 8) ^ sw)]);
    }
    // rescale + PV
#pragma unroll
    for (int m = 0; m < 2; ++m)
#pragma unroll
      for (int nt = 0; nt < 4; ++nt) {
        acc[m][nt][0] *= alpha[m][0];
        acc[m][nt][1] *= alpha[m][1];
        acc[m][nt][2] *= alpha[m][2];
        acc[m][nt][3] *= alpha[m][3];
        acc[m][nt] = mfma16(pa[m][0], vb[nt][0], acc[m][nt]);
        acc[m][nt] = mfma16(pa[m][1], vb[nt][1], acc[m][nt]);
      }
    __syncthreads();   // next tile staged + everyone done with cur
    cur ^= 1;
  }
  // epilogue
  float inv[2][4];
#pragma unroll
  for (int m = 0; m < 2; ++m)
#pragma unroll
    for (int r = 0; r < 4; ++r) inv[m][r] = 1.0f / lrow[m][r];
#pragma unroll
  for (int m = 0; m < 2; ++m)
#pragma unroll
    for (int nt = 0; nt < 4; ++nt) {
      int col = h * HD + nt * 16 + l16;
#pragma unroll
      for (int r = 0; r < 4; ++r) {
        int row = b * SEQ + qt * 128 + w * 32 + m * 16 + l4 * 4 + r;
        aout[(size_t)row * D_MODEL + col] = f2bf(acc[m][nt][r] * inv[m][r]);
      }
    }
}

// ---------------- output projection: out = attn @ Wo + bo (fp32 out) ----------------
// grid (8, 64), block 256; tile 64(M)x128(N), wave wc owns a 64x32 strip
__global__ __launch_bounds__(256) void out_gemm(
    const unsigned short* __restrict__ ah, const unsigned short* __restrict__ wthi,
    const unsigned short* __restrict__ wtlo, const float* __restrict__ bo,
    float* __restrict__ out) {
  const unsigned short* Bh = wthi + (size_t)3 * D_MODEL * D_MODEL;
  const unsigned short* Bl = wtlo + (size_t)3 * D_MODEL * D_MODEL;
  int bm = blockIdx.y, bn = blockIdx.x;
  int tid = threadIdx.x, lane = tid & 63, wc = tid >> 6;
  int l16 = lane & 15, l4 = lane >> 4;
  f4 acc[4][2];
  const f4 zf = {0.f, 0.f, 0.f, 0.f};
#pragma unroll
  for (int m = 0; m < 4; ++m)
#pragma unroll
    for (int n = 0; n < 2; ++n) acc[m][n] = zf;

  for (int kt = 0; kt < D_MODEL; kt += 32) {
    bf8 a[4], bhf[2], blf[2];
#pragma unroll
    for (int m = 0; m < 4; ++m)
      a[m] = *reinterpret_cast<const bf8*>(
          ah + (size_t)(bm * 64 + m * 16 + l16) * D_MODEL + kt + l4 * 8);
#pragma unroll
    for (int n = 0; n < 2; ++n) {
      size_t off = (size_t)(bn * 128 + wc * 32 + n * 16 + l16) * D_MODEL + kt + l4 * 8;
      bhf[n] = *reinterpret_cast<const bf8*>(Bh + off);
      blf[n] = *reinterpret_cast<const bf8*>(Bl + off);
    }
#pragma unroll
    for (int m = 0; m < 4; ++m)
#pragma unroll
      for (int n = 0; n < 2; ++n) {
        acc[m][n] = mfma16(a[m], bhf[n], acc[m][n]);
        acc[m][n] = mfma16(a[m], blf[n], acc[m][n]);
      }
  }
#pragma unroll
  for (int n = 0; n < 2; ++n) {
    int col = bn * 128 + wc * 32 + n * 16 + l16;
    float bb = bo[col];
#pragma unroll
    for (int m = 0; m < 4; ++m) {
      int row0 = bm * 64 + m * 16 + l4 * 4;
#pragma unroll
      for (int r = 0; r < 4; ++r)
        out[(size_t)(row0 + r) * D_MODEL + col] = acc[m][n][r] + bb;
    }
  }
}

extern "C" void kernel_launch(void* const* d_in, const int* in_sizes, int n_in,
                              void* d_out, int out_size, void* d_ws, size_t ws_size,
                              hipStream_t stream) {
  const float* Q  = (const float*)d_in[0];
  const float* K  = (const float*)d_in[1];
  const float* V  = (const float*)d_in[2];
  const float* Wq = (const float*)d_in[3];
  const float* bq = (const float*)d_in[4];
  const float* Wk = (const float*)d_in[5];
  const float* bk = (const float*)d_in[6];
  const float* Wv = (const float*)d_in[7];
  const float* bv = (const float*)d_in[8];
  const float* Wo = (const float*)d_in[9];
  const float* bo = (const float*)d_in[10];
  float* out = (float*)d_out;

  unsigned char* ws = (unsigned char*)d_ws;
  const size_t MB = 1024 * 1024;
  unsigned short* wthi = (unsigned short*)(ws);             // 4x [n][k] hi   (8 MB)
  unsigned short* wtlo = (unsigned short*)(ws + 8 * MB);    // 4x [n][k] lo   (8 MB)
  unsigned short* qh   = (unsigned short*)(ws + 16 * MB);   // q hi  [B,S,D]  (8 MB)
  unsigned short* kh   = (unsigned short*)(ws + 24 * MB);   // k hi           (8 MB)
  unsigned short* vt   = (unsigned short*)(ws + 32 * MB);   // V^T [B,H,d,S]  (8 MB)
  unsigned short* ah   = (unsigned short*)(ws + 40 * MB);   // attn out hi    (8 MB)

  prep_weights<<<dim3(32, 32, 4), 256, 0, stream>>>(Wq, Wk, Wv, Wo, wthi, wtlo);
  proj_kernel<<<dim3(8, 32, 3), 256, 0, stream>>>(Q, K, V, wthi, wtlo, bq, bk, bv,
                                                  qh, kh, vt);
  attn_kernel<<<dim3(16, NH, NB), 256, 0, stream>>>(qh, kh, vt, ah);
  out_gemm<<<dim3(8, 64), 256, 0, stream>>>(ah, wthi, wtlo, bo, out);
}

// Round 4
// 187.398 us; speedup vs baseline: 2.7755x; 1.6205x over previous
//
#include <hip/hip_runtime.h>
#include <cstdint>
#include <cstddef>

#define D_MODEL 1024
#define HD 64
#define NH 16
#define SEQ 2048
#define NB 2

typedef __attribute__((ext_vector_type(8))) short bf8;           // 8 bf16 (4 VGPR)
typedef __attribute__((ext_vector_type(8))) unsigned short us8;
typedef __attribute__((ext_vector_type(4))) unsigned short us4;
typedef __attribute__((ext_vector_type(4))) float f4;

__device__ __forceinline__ float bf2f(unsigned short u) {
  union { unsigned int i; float f; } c; c.i = ((unsigned int)u) << 16; return c.f;
}
__device__ __forceinline__ unsigned short f2bf(float x) {
  union { float f; unsigned int i; } c; c.f = x;
  unsigned int r = (c.i + 0x7FFFu + ((c.i >> 16) & 1u)) >> 16;   // RNE
  return (unsigned short)r;
}
// packed f32x2 -> bf16x2 (RNE), single HW op
__device__ __forceinline__ unsigned int pkbf(float lo, float hi) {
  unsigned int r;
  asm("v_cvt_pk_bf16_f32 %0, %1, %2" : "=v"(r) : "v"(lo), "v"(hi));
  return r;
}
// exp2 via v_exp_f32 (D = 2^S0)
__device__ __forceinline__ float ex2(float x) {
  float r;
  asm("v_exp_f32 %0, %1" : "=v"(r) : "v"(x));
  return r;
}
__device__ __forceinline__ f4 mfma16(bf8 a, bf8 b, f4 c) {
  return __builtin_amdgcn_mfma_f32_16x16x32_bf16(a, b, c, 0, 0, 0);
}
// async global->LDS, 16B per lane; LDS dest = wave-uniform base + lane*16
__device__ __forceinline__ void gl16(const unsigned short* g, unsigned short* l) {
  __builtin_amdgcn_global_load_lds(
      (const __attribute__((address_space(1))) unsigned int*)g,
      (__attribute__((address_space(3))) unsigned int*)l, 16, 0, 0);
}

#define QSCALE (0.125f * 1.44269504088896f)   // 1/sqrt(64) * log2(e)

// ---------------- convert fp32 inputs -> bf16 (once) ----------------
// grid (2048,1,3), block 256; thread handles 8 elements
__global__ __launch_bounds__(256) void convert_inputs(
    const float* __restrict__ Q, const float* __restrict__ K, const float* __restrict__ V,
    unsigned short* __restrict__ dq, unsigned short* __restrict__ dk,
    unsigned short* __restrict__ dv) {
  int z = blockIdx.z;
  const float* s = (z == 0) ? Q : (z == 1) ? K : V;
  unsigned short* d = (z == 0) ? dq : (z == 1) ? dk : dv;
  size_t i = ((size_t)blockIdx.x * 256 + threadIdx.x) * 8;
  float4 a = *reinterpret_cast<const float4*>(s + i);
  float4 b = *reinterpret_cast<const float4*>(s + i + 4);
  union { us8 v; unsigned int u[4]; } o;
  o.u[0] = pkbf(a.x, a.y); o.u[1] = pkbf(a.z, a.w);
  o.u[2] = pkbf(b.x, b.y); o.u[3] = pkbf(b.z, b.w);
  *reinterpret_cast<us8*>(d + i) = o.v;
}

// ---------------- prep: transpose + hi/lo split of the 4 weight matrices ----------------
// mat 0 (Wq) pre-scaled by QSCALE (folds softmax scale + log2e into q)
__global__ __launch_bounds__(256) void prep_weights(
    const float* __restrict__ Wq, const float* __restrict__ Wk,
    const float* __restrict__ Wv, const float* __restrict__ Wo,
    unsigned short* __restrict__ wthi, unsigned short* __restrict__ wtlo) {
  int mat = blockIdx.z;
  const float* W = (mat == 0) ? Wq : (mat == 1) ? Wk : (mat == 2) ? Wv : Wo;
  unsigned short* oh = wthi + (size_t)mat * D_MODEL * D_MODEL;
  unsigned short* ol = wtlo + (size_t)mat * D_MODEL * D_MODEL;
  __shared__ float ls[32][33];
  int nt = blockIdx.x * 32, kt = blockIdx.y * 32;
  int i = threadIdx.x >> 5;
  int j = threadIdx.x & 31;
#pragma unroll
  for (int ii = 0; ii < 4; ++ii) {
    int r = i + ii * 8;
    ls[r][j] = W[(size_t)(kt + r) * D_MODEL + nt + j];
  }
  __syncthreads();
#pragma unroll
  for (int ii = 0; ii < 4; ++ii) {
    int r = i + ii * 8;
    float v = ls[j][r];
    if (mat == 0) v *= QSCALE;
    unsigned short h = f2bf(v);
    size_t o = (size_t)(nt + r) * D_MODEL + kt + j;
    oh[o] = h;
    ol[o] = f2bf(v - bf2f(h));
  }
}

// ---------------- unified GEMM: C = A @ W^T(hi+lo) + bias, 4 epilogues ----------------
// z=0: q->qh, z=1: k->kh, z=2: v->vt (transposed), z=3: fp32 out
// 128x128 tile, BK=32, 4 waves 2x2, A/Bh/Bl all staged via global_load_lds,
// double-buffered, XOR-swizzled granules.
__global__ __launch_bounds__(256, 3) void gemm_kernel(
    const unsigned short* __restrict__ A0, const unsigned short* __restrict__ A1,
    const unsigned short* __restrict__ A2,
    const unsigned short* __restrict__ wth, const unsigned short* __restrict__ wtl,
    const float* __restrict__ b0, const float* __restrict__ b1,
    const float* __restrict__ b2, const float* __restrict__ b3,
    unsigned short* __restrict__ qh, unsigned short* __restrict__ kh,
    unsigned short* __restrict__ vt, float* __restrict__ o32, int zbase) {
  int z = zbase + blockIdx.z;
  const unsigned short* A = (z == 0) ? A0 : (z == 1) ? A1 : (z == 2) ? A2 : A0;
  const unsigned short* Bh = wth + ((size_t)z << 20);
  const unsigned short* Bl = wtl + ((size_t)z << 20);
  const float* bias = (z == 0) ? b0 : (z == 1) ? b1 : (z == 2) ? b2 : b3;
  float bsc = (z == 0) ? QSCALE : 1.0f;

  int bm = blockIdx.y, bn = blockIdx.x;
  int tid = threadIdx.x, lane = tid & 63, w = tid >> 6;
  int wr = w >> 1, wc = w & 1, l16 = lane & 15, l4 = lane >> 4;

  __shared__ unsigned short As[2][128 * 32];
  __shared__ unsigned short Bsh[2][128 * 32];
  __shared__ unsigned short Bsl[2][128 * 32];

  const unsigned short* Ab = A + (size_t)(bm * 128) * D_MODEL;
  const unsigned short* Bhb = Bh + (size_t)(bn * 128) * D_MODEL;
  const unsigned short* Blb = Bl + (size_t)(bn * 128) * D_MODEL;

  // staging coords: round p covers slot L = p*256+tid; row=L>>2, granule slot=L&3
  int r0 = tid >> 2, g0 = tid & 3;
  int r1 = (256 + tid) >> 2, g1 = tid & 3;
  int s0 = (r0 ^ (r0 >> 2)) & 3, s1 = (r1 ^ (r1 >> 2)) & 3;
  size_t so0 = (size_t)r0 * D_MODEL + ((g0 ^ s0) * 8);
  size_t so1 = (size_t)r1 * D_MODEL + ((g1 ^ s1) * 8);
  int ld0 = (w * 64) * 8;          // wave-uniform LDS base, p=0 (shorts)
  int ld1 = (256 + w * 64) * 8;    // p=1

  // frag read offsets (hoisted)
  int offA[4], offB[4];
#pragma unroll
  for (int m = 0; m < 4; ++m) {
    int row = wr * 64 + m * 16 + l16;
    int sw = (row ^ (row >> 2)) & 3;
    offA[m] = row * 32 + ((l4 ^ sw)) * 8;
  }
#pragma unroll
  for (int n = 0; n < 4; ++n) {
    int row = wc * 64 + n * 16 + l16;
    int sw = (row ^ (row >> 2)) & 3;
    offB[n] = row * 32 + ((l4 ^ sw)) * 8;
  }

  f4 acc[4][4];
  const f4 zf = {0.f, 0.f, 0.f, 0.f};
#pragma unroll
  for (int m = 0; m < 4; ++m)
#pragma unroll
    for (int n = 0; n < 4; ++n) acc[m][n] = zf;

  // prologue: stage tile 0
  gl16(Ab + so0, &As[0][ld0]);  gl16(Ab + so1, &As[0][ld1]);
  gl16(Bhb + so0, &Bsh[0][ld0]); gl16(Bhb + so1, &Bsh[0][ld1]);
  gl16(Blb + so0, &Bsl[0][ld0]); gl16(Blb + so1, &Bsl[0][ld1]);
  __syncthreads();

  int cur = 0;
  for (int i = 0; i < 32; ++i) {
    if (i < 31) {
      int ktn = (i + 1) * 32;
      gl16(Ab + ktn + so0, &As[cur ^ 1][ld0]);  gl16(Ab + ktn + so1, &As[cur ^ 1][ld1]);
      gl16(Bhb + ktn + so0, &Bsh[cur ^ 1][ld0]); gl16(Bhb + ktn + so1, &Bsh[cur ^ 1][ld1]);
      gl16(Blb + ktn + so0, &Bsl[cur ^ 1][ld0]); gl16(Blb + ktn + so1, &Bsl[cur ^ 1][ld1]);
    }
    bf8 a[4], bh[4], bl[4];
#pragma unroll
    for (int m = 0; m < 4; ++m)
      a[m] = *reinterpret_cast<const bf8*>(&As[cur][offA[m]]);
#pragma unroll
    for (int n = 0; n < 4; ++n) {
      bh[n] = *reinterpret_cast<const bf8*>(&Bsh[cur][offB[n]]);
      bl[n] = *reinterpret_cast<const bf8*>(&Bsl[cur][offB[n]]);
    }
#pragma unroll
    for (int m = 0; m < 4; ++m)
#pragma unroll
      for (int n = 0; n < 4; ++n) {
        acc[m][n] = mfma16(a[m], bh[n], acc[m][n]);
        acc[m][n] = mfma16(a[m], bl[n], acc[m][n]);
      }
    __syncthreads();
    cur ^= 1;
  }

#pragma unroll
  for (int n = 0; n < 4; ++n) {
    int col = bn * 128 + wc * 64 + n * 16 + l16;
    float bb = bias[col] * bsc;
#pragma unroll
    for (int m = 0; m < 4; ++m) {
      int row0 = bm * 128 + wr * 64 + m * 16 + l4 * 4;
      if (z == 0) {
#pragma unroll
        for (int r = 0; r < 4; ++r)
          qh[(size_t)(row0 + r) * D_MODEL + col] = f2bf(acc[m][n][r] + bb);
      } else if (z == 1) {
#pragma unroll
        for (int r = 0; r < 4; ++r)
          kh[(size_t)(row0 + r) * D_MODEL + col] = f2bf(acc[m][n][r] + bb);
      } else if (z == 2) {
        int bb2 = row0 >> 11, ss = row0 & (SEQ - 1);
        int hh2 = col >> 6, dd = col & 63;
        union { us4 s; uint2 u; } pk4;
        pk4.u.x = pkbf(acc[m][n][0] + bb, acc[m][n][1] + bb);
        pk4.u.y = pkbf(acc[m][n][2] + bb, acc[m][n][3] + bb);
        *reinterpret_cast<us4*>(vt + ((size_t)(bb2 * NH + hh2) * HD + dd) * SEQ + ss) = pk4.s;
      } else {
#pragma unroll
        for (int r = 0; r < 4; ++r)
          o32[(size_t)(row0 + r) * D_MODEL + col] = acc[m][n][r] + bb;
      }
    }
  }
}

// ---------------- flash attention, swapped-operand (register softmax) ----------------
// block 256 (4 waves), wave owns 32 q-rows; per KV-tile (64 keys) K/V^T staged
// to double-buffered LDS. QK^T computed SWAPPED (S^T = K*Q^T) so each lane owns
// one q-column with 16 k-scores in registers: softmax is in-register + 2 shfl.
// P^T redistributed to B-frag layout via cvt_pk + ds_bpermute (no LDS).
// PV computes O^T = V^T * P^T; epilogue transposes via freed LDS.
__global__ __launch_bounds__(256) void attn_kernel(
    const unsigned short* __restrict__ qh, const unsigned short* __restrict__ kh,
    const unsigned short* __restrict__ vt, unsigned short* __restrict__ aout) {
  // XCD-aware bijective swizzle: 512 blocks, 8 XCDs -> 64 contiguous per XCD
  int orig = blockIdx.x + (blockIdx.y << 4) + (blockIdx.z << 8);
  int swz = ((orig & 7) << 6) + (orig >> 3);
  int qt = swz & 15, h = (swz >> 4) & 15, b = swz >> 8;

  int tid = threadIdx.x;
  int lane = tid & 63, w = tid >> 6;
  int l16 = lane & 15, l4 = lane >> 4;
  int l8r = lane >> 3, l8c = lane & 7;

  __shared__ unsigned short lds[16384];   // [2][4096] K + [2][4096] V^T; reused as trbuf

  const unsigned short* Kh = kh + (size_t)b * SEQ * D_MODEL + h * HD;
  const unsigned short* Vt = vt + (size_t)(b * NH + h) * HD * SEQ;

  // q B-frags: B[k=d, col=q=l16]; rows qt*128 + w*32 + m*16 + l16
  bf8 qf[2][2];
#pragma unroll
  for (int m = 0; m < 2; ++m) {
    size_t qo = (size_t)(b * SEQ + qt * 128 + w * 32 + m * 16 + l16) * D_MODEL + h * HD + l4 * 8;
    qf[m][0] = *reinterpret_cast<const bf8*>(qh + qo);
    qf[m][1] = *reinterpret_cast<const bf8*>(qh + qo + 32);
  }

  const f4 zf = {0.f, 0.f, 0.f, 0.f};
  f4 acc[2][4];                 // O^T: acc[m][nt], rows d=nt*16+l4*4+r, col q=l16
  float mr[2] = {0.f, 0.f};     // per-lane running max (lane's q), defer-max
  float lr[2] = {0.f, 0.f};     // per-lane PARTIAL sum (this l4's 16 keys)
#pragma unroll
  for (int m = 0; m < 2; ++m)
#pragma unroll
    for (int nt = 0; nt < 4; ++nt) acc[m][nt] = zf;

  const int sgr = (l8c ^ l8r) * 8;   // pre-swizzled source granule
  const int sl1 = w, sl2 = w + 4;    // wave's two 1KB staging slices

  // bpermute addresses (wave-lane*4): src l4 = (own_l4&1)*2 + jh
  const int a0 = (l16 + (((l4 & 1) * 2 + 0) << 4)) << 2;
  const int a1 = (l16 + (((l4 & 1) * 2 + 1) << 4)) << 2;
  const bool hi2 = (l4 >> 1) != 0;

  // stage tile 0
  gl16(Kh + (size_t)(8 * sl1 + l8r) * D_MODEL + sgr, &lds[0 * 4096 + sl1 * 512]);
  gl16(Kh + (size_t)(8 * sl2 + l8r) * D_MODEL + sgr, &lds[0 * 4096 + sl2 * 512]);
  gl16(Vt + (size_t)(8 * sl1 + l8r) * SEQ + sgr, &lds[8192 + sl1 * 512]);
  gl16(Vt + (size_t)(8 * sl2 + l8r) * SEQ + sgr, &lds[8192 + sl2 * 512]);
  __syncthreads();

  int cur = 0;
  for (int kv = 0; kv < SEQ / 64; ++kv) {
    if (kv < SEQ / 64 - 1) {
      int k0n = (kv + 1) * 64;
      unsigned short* kd = &lds[(cur ^ 1) * 4096];
      unsigned short* vd = &lds[8192 + (cur ^ 1) * 4096];
      gl16(Kh + (size_t)(k0n + 8 * sl1 + l8r) * D_MODEL + sgr, kd + sl1 * 512);
      gl16(Kh + (size_t)(k0n + 8 * sl2 + l8r) * D_MODEL + sgr, kd + sl2 * 512);
      gl16(Vt + (size_t)(8 * sl1 + l8r) * SEQ + k0n + sgr, vd + sl1 * 512);
      gl16(Vt + (size_t)(8 * sl2 + l8r) * SEQ + k0n + sgr, vd + sl2 * 512);
    }
    const unsigned short* khb = &lds[cur * 4096];
    const unsigned short* vlb = &lds[8192 + cur * 4096];

    // K A-frags: A[row=key(tile-local), k=d]
    bf8 kb[4][2];
#pragma unroll
    for (int c = 0; c < 4; ++c) {
      int row = c * 16 + l16, sw = l16 & 7;
      kb[c][0] = *reinterpret_cast<const bf8*>(&khb[row * 64 + ((l4 ^ sw) * 8)]);
      kb[c][1] = *reinterpret_cast<const bf8*>(&khb[row * 64 + (((4 + l4) ^ sw) * 8)]);
    }
    // swapped QK^T: sc[m][c] = S^T rows key=c*16+l4*4+r, col q=l16
    f4 sc[2][4];
#pragma unroll
    for (int m = 0; m < 2; ++m)
#pragma unroll
      for (int c = 0; c < 4; ++c) {
        f4 s = zf;
        s = mfma16(kb[c][0], qf[m][0], s);
        s = mfma16(kb[c][1], qf[m][1], s);
        sc[m][c] = s;
      }
    // V^T A-frags (independent; overlaps softmax)
    bf8 vb[4][2];
#pragma unroll
    for (int nt = 0; nt < 4; ++nt) {
      int row = nt * 16 + l16, sw = l16 & 7;
      vb[nt][0] = *reinterpret_cast<const bf8*>(&vlb[row * 64 + ((l4 ^ sw) * 8)]);
      vb[nt][1] = *reinterpret_cast<const bf8*>(&vlb[row * 64 + (((4 + l4) ^ sw) * 8)]);
    }

#pragma unroll
    for (int m = 0; m < 2; ++m) {
      // max over this lane's 16 scores (tree) then across l4 groups
      float tc[4];
#pragma unroll
      for (int c = 0; c < 4; ++c)
        tc[c] = fmaxf(fmaxf(sc[m][c][0], sc[m][c][1]), fmaxf(sc[m][c][2], sc[m][c][3]));
      float tm = fmaxf(fmaxf(tc[0], tc[1]), fmaxf(tc[2], tc[3]));
      tm = fmaxf(tm, __shfl_xor(tm, 16));
      tm = fmaxf(tm, __shfl_xor(tm, 32));
      // defer-max (THR=8): rescale only if max grew beyond headroom
      if (__any(tm > mr[m] + 8.0f)) {
        float mn = fmaxf(mr[m], tm);
        float al = ex2(mr[m] - mn);
        mr[m] = mn;
        lr[m] *= al;
#pragma unroll
        for (int nt = 0; nt < 4; ++nt) {
          acc[m][nt][0] *= al; acc[m][nt][1] *= al;
          acc[m][nt][2] *= al; acc[m][nt][3] *= al;
        }
      }
      // P = exp2(s - m), partial row-sum in-register
#pragma unroll
      for (int c = 0; c < 4; ++c)
#pragma unroll
        for (int r = 0; r < 4; ++r) {
          float p = ex2(sc[m][c][r] - mr[m]);
          sc[m][c][r] = p;
          lr[m] += p;
        }
      // pack P^T to bf16 words: W[c][w] = keys {16c+4*l4+2w, +1}
      int W[4][2];
#pragma unroll
      for (int c = 0; c < 4; ++c) {
        W[c][0] = (int)pkbf(sc[m][c][0], sc[m][c][1]);
        W[c][1] = (int)pkbf(sc[m][c][2], sc[m][c][3]);
      }
      // redistribute to B-frag layout: lane needs keys 32h + l4*8 + j
      bf8 pb[2];
#pragma unroll
      for (int hh = 0; hh < 2; ++hh) {
        int c0 = 2 * hh, c1 = 2 * hh + 1;
        int w0a = __builtin_amdgcn_ds_bpermute(a0, W[c0][0]);
        int w0b = __builtin_amdgcn_ds_bpermute(a0, W[c1][0]);
        int w1a = __builtin_amdgcn_ds_bpermute(a0, W[c0][1]);
        int w1b = __builtin_amdgcn_ds_bpermute(a0, W[c1][1]);
        int w2a = __builtin_amdgcn_ds_bpermute(a1, W[c0][0]);
        int w2b = __builtin_amdgcn_ds_bpermute(a1, W[c1][0]);
        int w3a = __builtin_amdgcn_ds_bpermute(a1, W[c0][1]);
        int w3b = __builtin_amdgcn_ds_bpermute(a1, W[c1][1]);
        union { int4 i; bf8 v; } u;
        u.i.x = hi2 ? w0b : w0a;
        u.i.y = hi2 ? w1b : w1a;
        u.i.z = hi2 ? w2b : w2a;
        u.i.w = hi2 ? w3b : w3a;
        pb[hh] = u.v;
      }
      // PV: O^T += V^T * P^T
#pragma unroll
      for (int nt = 0; nt < 4; ++nt) {
        acc[m][nt] = mfma16(vb[nt][0], pb[0], acc[m][nt]);
        acc[m][nt] = mfma16(vb[nt][1], pb[1], acc[m][nt]);
      }
    }
    __syncthreads();
    cur ^= 1;
  }

  // epilogue: finish row-sums, normalize, transpose O^T -> O via freed LDS
  float inv[2];
#pragma unroll
  for (int m = 0; m < 2; ++m) {
    float t = lr[m];
    t += __shfl_xor(t, 16);
    t += __shfl_xor(t, 32);
    inv[m] = 1.0f / t;
  }
#pragma unroll
  for (int m = 0; m < 2; ++m) {
    int q = w * 32 + m * 16 + l16;
    int sw = (q & 7) << 3;
#pragma unroll
    for (int nt = 0; nt < 4; ++nt) {
      uint2 pw;
      pw.x = pkbf(acc[m][nt][0] * inv[m], acc[m][nt][1] * inv[m]);
      pw.y = pkbf(acc[m][nt][2] * inv[m], acc[m][nt][3] * inv[m]);
      int d0 = nt * 16 + l4 * 4;
      *reinterpret_cast<uint2*>(&lds[q * 64 + (d0 ^ sw)]) = pw;
    }
  }
  __syncthreads();
  {
    int q = tid >> 1, dh = (tid & 1) * 32, sw = (q & 7) << 3;
    size_t orow = ((size_t)(b * SEQ + qt * 128 + q)) * D_MODEL + h * HD + dh;
#pragma unroll
    for (int j = 0; j < 4; ++j) {
      us8 vv = *reinterpret_cast<const us8*>(&lds[q * 64 + ((dh + j * 8) ^ sw)]);
      *reinterpret_cast<us8*>(&aout[orow + j * 8]) = vv;
    }
  }
}

extern "C" void kernel_launch(void* const* d_in, const int* in_sizes, int n_in,
                              void* d_out, int out_size, void* d_ws, size_t ws_size,
                              hipStream_t stream) {
  const float* Q  = (const float*)d_in[0];
  const float* K  = (const float*)d_in[1];
  const float* V  = (const float*)d_in[2];
  const float* Wq = (const float*)d_in[3];
  const float* bq = (const float*)d_in[4];
  const float* Wk = (const float*)d_in[5];
  const float* bk = (const float*)d_in[6];
  const float* Wv = (const float*)d_in[7];
  const float* bv = (const float*)d_in[8];
  const float* Wo = (const float*)d_in[9];
  const float* bo = (const float*)d_in[10];
  float* out = (float*)d_out;

  // workspace (56 MB) + d_out doubles as Q/K bf16 scratch (overwritten by final GEMM)
  unsigned char* ws = (unsigned char*)d_ws;
  const size_t MB = 1024 * 1024;
  unsigned short* wthi = (unsigned short*)(ws);             // 4x W^T hi      (8 MB)
  unsigned short* wtlo = (unsigned short*)(ws + 8 * MB);    // 4x W^T lo      (8 MB)
  unsigned short* qh   = (unsigned short*)(ws + 16 * MB);   // q bf16 [B,S,D] (8 MB)
  unsigned short* kh   = (unsigned short*)(ws + 24 * MB);   // k bf16         (8 MB)
  unsigned short* vt   = (unsigned short*)(ws + 32 * MB);   // V^T [B,H,d,S]  (8 MB)
  unsigned short* ah   = (unsigned short*)(ws + 40 * MB);   // attn out bf16  (8 MB)
  unsigned short* vbf  = (unsigned short*)(ws + 48 * MB);   // V input bf16   (8 MB)
  unsigned short* qbf  = (unsigned short*)d_out;            // Q input bf16 (scratch in d_out)
  unsigned short* kbf  = (unsigned short*)d_out + 4 * MB;   // K input bf16 (scratch in d_out)

  convert_inputs<<<dim3(2048, 1, 3), 256, 0, stream>>>(Q, K, V, qbf, kbf, vbf);
  prep_weights<<<dim3(32, 32, 4), 256, 0, stream>>>(Wq, Wk, Wv, Wo, wthi, wtlo);
  gemm_kernel<<<dim3(8, 32, 3), 256, 0, stream>>>(qbf, kbf, vbf, wthi, wtlo,
                                                  bq, bk, bv, bo, qh, kh, vt, out, 0);
  attn_kernel<<<dim3(16, NH, NB), 256, 0, stream>>>(qh, kh, vt, ah);
  gemm_kernel<<<dim3(8, 32, 1), 256, 0, stream>>>(ah, ah, ah, wthi, wtlo,
                                                  bq, bk, bv, bo, qh, kh, vt, out, 3);
}